// Round 11
// baseline (107.101 us; speedup 1.0000x reference)
//
#include <hip/hip_runtime.h>
#include <hip/hip_bf16.h>

#define NTOK  2048          // F*H*W = 2*32*32
#define INNER 512
#define KDIM  512
#define QKVP  1536          // qkv row pitch (bf16 elems)

typedef __attribute__((ext_vector_type(8))) short bf16x8;
typedef __attribute__((ext_vector_type(4))) float f32x4;

// fp32 -> bf16 bits, round-to-nearest-even
__device__ __forceinline__ unsigned short f2b(float f) {
  unsigned int u = __float_as_uint(f);
  return (unsigned short)((u + 0x7FFFu + ((u >> 16) & 1u)) >> 16);
}

// async global->LDS, 16 bytes per lane (wave-linear LDS mapping required)
__device__ __forceinline__ void async_copy16(const unsigned short* g, unsigned short* l) {
  __builtin_amdgcn_global_load_lds((const __attribute__((address_space(1))) void*)g,
                                   (__attribute__((address_space(3))) void*)l, 16, 0, 0);
}

// ---------------- K1: qkv = x(fp32) @ w_qkv(fp32) -> bf16, fully fused ----------------
// BM=64, BN=64, BK=32; grid 24x32 = 768 blocks. A: row-major in-register convert.
// B: transposed load (8 k-strided dwords per thread -> one ds_write_b128 of [n][k]).
__global__ __launch_bounds__(256, 3) void gemm_qkv_f(const float* __restrict__ x,
                                                     const float* __restrict__ w_qkv,
                                                     unsigned short* __restrict__ C) {
  constexpr int BK = 32, N = 1536, K = 512;
  __shared__ __align__(16) unsigned short As[64 * BK];
  __shared__ __align__(16) unsigned short Bs[64 * BK];
  const int tid = threadIdx.x, lane = tid & 63, wave = tid >> 6;
  const int m0 = blockIdx.y * 64, n0 = blockIdx.x * 64;
  const int wm = (wave >> 1) * 32, wn = (wave & 1) * 32;
  const int ar = tid >> 2, ac = (tid & 3) * 8;       // A: row ar, k-chunk ac
  const int bn = tid >> 2, bk8 = (tid & 3) * 8;      // B: col bn, k-chunk bk8
  const int fr = lane & 15, fk = (lane >> 4) * 8;

  f32x4 acc[2][2] = {};

  for (int k0 = 0; k0 < K; k0 += BK) {
    // A tile: x[m0+ar][k0+ac..+7] fp32 -> bf16
    {
      const float* ap = x + (size_t)(m0 + ar) * K + k0 + ac;
      float4 a0 = *(const float4*)(ap);
      float4 a1 = *(const float4*)(ap + 4);
      bf16x8 av;
      av[0] = (short)f2b(a0.x); av[1] = (short)f2b(a0.y);
      av[2] = (short)f2b(a0.z); av[3] = (short)f2b(a0.w);
      av[4] = (short)f2b(a1.x); av[5] = (short)f2b(a1.y);
      av[6] = (short)f2b(a1.z); av[7] = (short)f2b(a1.w);
      *(bf16x8*)&As[ar * BK + ac] = av;
    }
    // B tile: w_qkv[k0+bk8+j][n0+bn] fp32 -> Bs[bn][bk8+j] bf16
    {
      const float* bp = w_qkv + (size_t)(k0 + bk8) * N + n0 + bn;
      bf16x8 bv;
#pragma unroll
      for (int j = 0; j < 8; ++j) bv[j] = (short)f2b(bp[(size_t)j * N]);
      *(bf16x8*)&Bs[bn * BK + bk8] = bv;
    }
    __syncthreads();

    bf16x8 af[2], bfr[2];
#pragma unroll
    for (int i = 0; i < 2; ++i) af[i] = *(const bf16x8*)&As[(wm + i * 16 + fr) * BK + fk];
#pragma unroll
    for (int j = 0; j < 2; ++j) bfr[j] = *(const bf16x8*)&Bs[(wn + j * 16 + fr) * BK + fk];
#pragma unroll
    for (int i = 0; i < 2; ++i)
#pragma unroll
      for (int j = 0; j < 2; ++j)
        acc[i][j] = __builtin_amdgcn_mfma_f32_16x16x32_bf16(af[i], bfr[j], acc[i][j], 0, 0, 0);
    __syncthreads();
  }

  const int er = (lane >> 4) * 4, ec = lane & 15;
#pragma unroll
  for (int i = 0; i < 2; ++i)
#pragma unroll
    for (int j = 0; j < 2; ++j) {
      const int col = n0 + wn + j * 16 + ec;
#pragma unroll
      for (int rr = 0; rr < 4; ++rr) {
        const int row = m0 + wm + i * 16 + er + rr;
        C[(size_t)row * N + col] = f2b(acc[i][j][rr]);
      }
    }
}

// ---------------- K2: MFMA flash attention, key-split, inline lists ----------------
// Block = (16-pos tile, head-pair). 256 threads = 4 waves = 2 heads x 2 key-halves.
__global__ __launch_bounds__(256) void attn_mfma(const unsigned short* __restrict__ qkv,
                                                 unsigned short* __restrict__ O) {
  __shared__ __align__(16) int list[192];
  __shared__ __align__(16) float mOd[2][16][72];
  __shared__ float mM[2][16], mL[2][16];
  __shared__ int cntS;

  const int tid = threadIdx.x;
  const int hp = blockIdx.y;   // head pair 0..3

  if (blockIdx.x == 128) {  // output row 0 = V(token 0)
    if (tid < 128) O[hp * 128 + tid] = qkv[1024 + hp * 128 + tid];
    return;
  }
  const int pt = blockIdx.x;
  const int f  = pt >> 6;
  const int hh = (pt >> 1) & 31;
  const int w0 = (pt & 1) << 4;
  const int base_i = (f << 10) | (hh << 5) | w0;

  // ---- build packed causal key list (slot 0 = BOS) ----
  if (tid < 192) list[tid] = 0x7FFFFFFF;
  if (tid == 0) { list[0] = 0; cntS = 1; }
  __syncthreads();
  if (tid >= 1 && tid <= 160) {
    int cc = tid - 1;
    int p = cc / 20, wo = cc - p * 20;
    int ff = (p < 5) ? 0 : 1;
    int h2 = hh - 2 + ((p < 5) ? p : (p - 5));
    bool ok = (p < 5) ? ((f == 1) ? (h2 >= 0 && h2 <= 31) : (p <= 2 && h2 >= 0))
                      : (f == 1 && h2 >= 0);
    if (ok) {
      bool diag = (ff == f) && (h2 == hh);
      int wlo = max(0, w0 - 2);
      int whi = min(31, diag ? (w0 + 15) : (w0 + 17));
      int w2 = wlo + wo;
      if (w2 <= whi) {
        int pos = atomicAdd(&cntS, 1);
        list[pos] = ((ff << 10) | (h2 << 5) | w2) + 1;
      }
    }
  }
  __syncthreads();
  const int nsub = (cntS + 15) >> 4;

  const int lane = tid & 63;
  const int wave = tid >> 6;      // 0..3
  const int hw   = wave >> 1;     // head within pair
  const int half = wave & 1;
  const int head = hp * 2 + hw;
  const int quad = lane >> 4;
  const int ec   = lane & 15;

  const int i_q = base_i + ec;
  const int tq  = min(i_q + 1, 2047);
  const unsigned short* qrow = qkv + (size_t)tq * QKVP + head * 64 + quad * 8;
  const bf16x8 qb0 = *(const bf16x8*)(qrow);
  const bf16x8 qb1 = *(const bf16x8*)(qrow + 32);

  f32x4 Od[4] = {{0,0,0,0},{0,0,0,0},{0,0,0,0},{0,0,0,0}};
  float m = -1e30f, l = 0.0f;

  for (int sub = half; sub < nsub; sub += 2) {
    const int base = sub * 16;
    const int tok_e = list[base + ec];
    const int4 tokv = *(const int4*)&list[base + quad * 4];
    const int tk[4] = {tokv.x, tokv.y, tokv.z, tokv.w};

    f32x4 S = {0, 0, 0, 0};
    {
      const int t0 = (tok_e > 2047) ? 0 : tok_e;
      const unsigned short* kr = qkv + (size_t)t0 * QKVP + 512 + head * 64 + quad * 8;
      const bf16x8 kf0 = *(const bf16x8*)(kr);
      const bf16x8 kf1 = *(const bf16x8*)(kr + 32);
      S = __builtin_amdgcn_mfma_f32_16x16x32_bf16(kf0, qb0, S, 0, 0, 0);
      S = __builtin_amdgcn_mfma_f32_16x16x32_bf16(kf1, qb1, S, 0, 0, 0);
    }

    float Sm[4];
#pragma unroll
    for (int r = 0; r < 4; ++r) {
      const int tok = tk[r];
      const int idx = tok - 1;
      const bool v = (tok == 0) ||
                     ((idx <= i_q) && ((unsigned)((idx & 31) - (w0 + ec) + 2) <= 4u));
      Sm[r] = v ? S[r] * 0.125f : -1e30f;
    }
    float mx = fmaxf(fmaxf(Sm[0], Sm[1]), fmaxf(Sm[2], Sm[3]));
    mx = fmaxf(mx, __shfl_xor(mx, 16, 64));
    mx = fmaxf(mx, __shfl_xor(mx, 32, 64));
    const float mn = fmaxf(m, mx);
    const float corr = __expf(m - mn);
    m = mn;
    const float p0 = __expf(Sm[0] - mn);
    const float p1 = __expf(Sm[1] - mn);
    const float p2 = __expf(Sm[2] - mn);
    const float p3 = __expf(Sm[3] - mn);
    float rs = (p0 + p1) + (p2 + p3);
    rs += __shfl_xor(rs, 16, 64);
    rs += __shfl_xor(rs, 32, 64);
    l = l * corr + rs;

    bf16x8 pf;
    pf[0] = (short)f2b(p0); pf[1] = (short)f2b(p1);
    pf[2] = (short)f2b(p2); pf[3] = (short)f2b(p3);
    pf[4] = 0; pf[5] = 0; pf[6] = 0; pf[7] = 0;

    const unsigned short* vp[4];
#pragma unroll
    for (int j = 0; j < 4; ++j) {
      const int tv = (tk[j] > 2047) ? 0 : tk[j];
      vp[j] = qkv + (size_t)tv * QKVP + 1024 + head * 64 + ec;
    }
#pragma unroll
    for (int dt = 0; dt < 4; ++dt) {
      bf16x8 vf;
#pragma unroll
      for (int j = 0; j < 4; ++j) vf[j] = (short)vp[j][dt * 16];
      vf[4] = 0; vf[5] = 0; vf[6] = 0; vf[7] = 0;
#pragma unroll
      for (int r = 0; r < 4; ++r) Od[dt][r] *= corr;
      Od[dt] = __builtin_amdgcn_mfma_f32_16x16x32_bf16(vf, pf, Od[dt], 0, 0, 0);
    }
  }

  // merge the two key-halves of this head
  if (half == 1) {
#pragma unroll
    for (int dt = 0; dt < 4; ++dt)
      *(f32x4*)&mOd[hw][ec][dt * 16 + quad * 4] = Od[dt];
    if (quad == 0) { mM[hw][ec] = m; mL[hw][ec] = l; }
  }
  __syncthreads();
  if (half == 0 && i_q <= 2046) {
    const float m1 = mM[hw][ec], l1 = mL[hw][ec];
    const float mm = fmaxf(m, m1);
    const float c0 = __expf(m - mm), c1 = __expf(m1 - mm);
    const float rl = 1.0f / (l * c0 + l1 * c1);
    unsigned short* ob = O + (size_t)(i_q + 1) * 512 + head * 64 + quad * 4;
#pragma unroll
    for (int dt = 0; dt < 4; ++dt) {
      const f32x4 o1 = *(const f32x4*)&mOd[hw][ec][dt * 16 + quad * 4];
      ushort4 u;
      u.x = f2b((Od[dt][0] * c0 + o1[0] * c1) * rl);
      u.y = f2b((Od[dt][1] * c0 + o1[1] * c1) * rl);
      u.z = f2b((Od[dt][2] * c0 + o1[2] * c1) * rl);
      u.w = f2b((Od[dt][3] * c0 + o1[3] * c1) * rl);
      *(ushort4*)(ob + dt * 16) = u;
    }
  }
}

// ---------------- K3: out = Ob @ w_out(fp32) + bias -> fp32, fused transpose ----------------
// BM=32, BN=64, BK=32; grid 8x64 = 512 blocks. A: async-LDS. B: transposed fp32 load.
__global__ __launch_bounds__(256, 4) void gemm_out_f(const unsigned short* __restrict__ A,
                                                     const float* __restrict__ w_out,
                                                     const float* __restrict__ bias,
                                                     float* __restrict__ C) {
  constexpr int BK = 32, N = 512, K = 512;
  __shared__ __align__(16) unsigned short As[32 * BK];
  __shared__ __align__(16) unsigned short Bs[64 * BK];
  const int tid = threadIdx.x, lane = tid & 63, wave = tid >> 6;
  const int m0 = blockIdx.y * 32, n0 = blockIdx.x * 64;
  const int wm = (wave >> 1) * 16, wn = (wave & 1) * 32;
  const int li = tid * 8, r = li >> 5, c = li & 31;
  const int bn = tid >> 2, bk8 = (tid & 3) * 8;
  const int fr = lane & 15, fk = (lane >> 4) * 8;

  f32x4 acc[2] = {};

  for (int k0 = 0; k0 < K; k0 += BK) {
    if (tid < 128) async_copy16(A + (size_t)(m0 + r) * K + k0 + c, &As[li]);  // waves 0,1
    {
      const float* bp = w_out + (size_t)(k0 + bk8) * N + n0 + bn;
      bf16x8 bv;
#pragma unroll
      for (int j = 0; j < 8; ++j) bv[j] = (short)f2b(bp[(size_t)j * N]);
      *(bf16x8*)&Bs[bn * BK + bk8] = bv;
    }
    __syncthreads();
    bf16x8 af, bfr[2];
    af = *(const bf16x8*)&As[(wm + fr) * BK + fk];
#pragma unroll
    for (int j = 0; j < 2; ++j) bfr[j] = *(const bf16x8*)&Bs[(wn + j * 16 + fr) * BK + fk];
#pragma unroll
    for (int j = 0; j < 2; ++j)
      acc[j] = __builtin_amdgcn_mfma_f32_16x16x32_bf16(af, bfr[j], acc[j], 0, 0, 0);
    __syncthreads();
  }

  const int er = (lane >> 4) * 4, ec = lane & 15;
#pragma unroll
  for (int j = 0; j < 2; ++j) {
    const int col = n0 + wn + j * 16 + ec;
    const float b = bias[col];
#pragma unroll
    for (int rr = 0; rr < 4; ++rr) {
      const int row = m0 + wm + er + rr;
      C[(size_t)row * N + col] = acc[j][rr] + b;
    }
  }
}

// ---------------- launch ----------------

extern "C" void kernel_launch(void* const* d_in, const int* in_sizes, int n_in,
                              void* d_out, int out_size, void* d_ws, size_t ws_size,
                              hipStream_t stream) {
  const float* x     = (const float*)d_in[0];
  const float* w_qkv = (const float*)d_in[1];
  const float* w_out = (const float*)d_in[2];
  const float* b_out = (const float*)d_in[3];
  float* out = (float*)d_out;

  char* ws = (char*)d_ws;
  unsigned short* qkvb = (unsigned short*)(ws);            // 2048x1536 bf16
  unsigned short* Ob   = (unsigned short*)(ws + 6291456);  // 2048x512  bf16

  hipLaunchKernelGGL(gemm_qkv_f, dim3(24, 32), dim3(256), 0, stream, x, w_qkv, qkvb);

  hipLaunchKernelGGL(attn_mfma, dim3(129, 4), dim3(256), 0, stream, qkvb, Ob);

  hipLaunchKernelGGL(gemm_out_f, dim3(8, 64), dim3(256), 0, stream, Ob, w_out, b_out, out);
}

// Round 12
// 96.213 us; speedup vs baseline: 1.1132x; 1.1132x over previous
//
#include <hip/hip_runtime.h>
#include <hip/hip_bf16.h>

#define NTOK  2048          // F*H*W = 2*32*32
#define INNER 512
#define KDIM  512
#define QKVP  1536          // qkv row pitch (bf16 elems)

typedef __attribute__((ext_vector_type(8))) short bf16x8;
typedef __attribute__((ext_vector_type(4))) float f32x4;

// fp32 -> bf16 bits, round-to-nearest-even
__device__ __forceinline__ unsigned short f2b(float f) {
  unsigned int u = __float_as_uint(f);
  return (unsigned short)((u + 0x7FFFu + ((u >> 16) & 1u)) >> 16);
}

// async global->LDS, 16 bytes per lane (wave-linear LDS mapping required)
__device__ __forceinline__ void async_copy16(const unsigned short* g, unsigned short* l) {
  __builtin_amdgcn_global_load_lds((const __attribute__((address_space(1))) void*)g,
                                   (__attribute__((address_space(3))) void*)l, 16, 0, 0);
}

// ---------------- prep: weight transposes + x conversion + neighbor lists ----------------
// blocks 0..767:    w_qkv [512][1536] -> wqkvT [1536][512] bf16
// blocks 768..1023: w_out [512][512]  -> woutT [512][512]  bf16
// blocks 1024..1151: packed causal key list for tile pt = b-1024
// blocks 1152..2175: x fp32 -> xb bf16 (4 elems/thread)
__global__ __launch_bounds__(256) void prep(const float* __restrict__ w_qkv,
                                            const float* __restrict__ w_out,
                                            const float* __restrict__ x,
                                            unsigned short* __restrict__ wqkvT,
                                            unsigned short* __restrict__ woutT,
                                            unsigned short* __restrict__ xb,
                                            int* __restrict__ glist,
                                            int* __restrict__ gcnt) {
  __shared__ float tile[32][33];
  __shared__ int list[192];
  __shared__ int cntS;
  const int tid = threadIdx.x;
  int b = blockIdx.x;

  if (b >= 1152) {  // x conversion
    const int i = (b - 1152) * 1024 + tid * 4;
    float4 v = *(const float4*)(x + i);
    ushort4 o;
    o.x = f2b(v.x); o.y = f2b(v.y); o.z = f2b(v.z); o.w = f2b(v.w);
    *(ushort4*)(xb + i) = o;
    return;
  }

  if (b < 1024) {  // weight transpose
    const float* in; unsigned short* out; int K, N, bx, by;
    if (b < 768) { in = w_qkv; out = wqkvT; K = 512; N = 1536; bx = b % 48; by = b / 48; }
    else { int bb = b - 768; in = w_out; out = woutT; K = 512; N = 512; bx = bb & 15; by = bb >> 4; }
    const int k0 = by * 32, n0 = bx * 32;
    const int r = tid >> 3, c4 = (tid & 7) * 4;
    float4 v = *(const float4*)(in + (size_t)(k0 + r) * N + n0 + c4);
    tile[r][c4 + 0] = v.x; tile[r][c4 + 1] = v.y;
    tile[r][c4 + 2] = v.z; tile[r][c4 + 3] = v.w;
    __syncthreads();
    ushort4 o;
    o.x = f2b(tile[c4 + 0][r]);
    o.y = f2b(tile[c4 + 1][r]);
    o.z = f2b(tile[c4 + 2][r]);
    o.w = f2b(tile[c4 + 3][r]);
    *(ushort4*)(out + (size_t)(n0 + r) * K + k0 + c4) = o;
    return;
  }

  // ---- neighbor list for one 16-w tile ----
  const int pt = b - 1024;
  const int f  = pt >> 6;
  const int hh = (pt >> 1) & 31;
  const int w0 = (pt & 1) << 4;

  if (tid < 192) list[tid] = 0x7FFFFFFF;
  if (tid == 0) { list[0] = 0; cntS = 1; }
  __syncthreads();
  if (tid >= 1 && tid <= 160) {
    int cc = tid - 1;
    int p = cc / 20, wo = cc - p * 20;
    int ff = (p < 5) ? 0 : 1;
    int h2 = hh - 2 + ((p < 5) ? p : (p - 5));
    bool ok = (p < 5) ? ((f == 1) ? (h2 >= 0 && h2 <= 31) : (p <= 2 && h2 >= 0))
                      : (f == 1 && h2 >= 0);
    if (ok) {
      bool diag = (ff == f) && (h2 == hh);
      int wlo = max(0, w0 - 2);
      int whi = min(31, diag ? (w0 + 15) : (w0 + 17));
      int w2 = wlo + wo;
      if (w2 <= whi) {
        int pos = atomicAdd(&cntS, 1);
        list[pos] = ((ff << 10) | (h2 << 5) | w2) + 1;
      }
    }
  }
  __syncthreads();
  if (tid < 192) glist[pt * 192 + tid] = list[tid];
  if (tid == 0) gcnt[pt] = cntS;
}

// ---------------- GEMM1: qkv = xb @ wqkvT^T -> bf16 ----------------
// BM=64, BN=64, BK=32; grid 24x32 = 768 blocks (3/CU). Both operands async-LDS.
__global__ __launch_bounds__(256, 4) void gemm_qkv(const unsigned short* __restrict__ A,
                                                   const unsigned short* __restrict__ Bt,
                                                   unsigned short* __restrict__ C) {
  constexpr int BK = 32, N = 1536, K = 512;
  __shared__ __align__(16) unsigned short As[64 * BK];
  __shared__ __align__(16) unsigned short Bs[64 * BK];
  const int tid = threadIdx.x, lane = tid & 63, wave = tid >> 6;
  const int m0 = blockIdx.y * 64, n0 = blockIdx.x * 64;
  const int wm = (wave >> 1) * 32, wn = (wave & 1) * 32;
  const int li = tid * 8, r = li >> 5, c = li & 31;   // 64x32: 8 elems/thread
  const int fr = lane & 15, fk = (lane >> 4) * 8;

  f32x4 acc[2][2] = {};

  for (int k0 = 0; k0 < K; k0 += BK) {
    async_copy16(A  + (size_t)(m0 + r) * K + k0 + c, &As[li]);
    async_copy16(Bt + (size_t)(n0 + r) * K + k0 + c, &Bs[li]);
    __syncthreads();
    bf16x8 af[2], bfr[2];
#pragma unroll
    for (int i = 0; i < 2; ++i) af[i] = *(const bf16x8*)&As[(wm + i * 16 + fr) * BK + fk];
#pragma unroll
    for (int j = 0; j < 2; ++j) bfr[j] = *(const bf16x8*)&Bs[(wn + j * 16 + fr) * BK + fk];
#pragma unroll
    for (int i = 0; i < 2; ++i)
#pragma unroll
      for (int j = 0; j < 2; ++j)
        acc[i][j] = __builtin_amdgcn_mfma_f32_16x16x32_bf16(af[i], bfr[j], acc[i][j], 0, 0, 0);
    __syncthreads();
  }

  const int er = (lane >> 4) * 4, ec = lane & 15;
#pragma unroll
  for (int i = 0; i < 2; ++i)
#pragma unroll
    for (int j = 0; j < 2; ++j) {
      const int col = n0 + wn + j * 16 + ec;
#pragma unroll
      for (int rr = 0; rr < 4; ++rr) {
        const int row = m0 + wm + i * 16 + er + rr;
        C[(size_t)row * N + col] = f2b(acc[i][j][rr]);
      }
    }
}

// ---------------- GEMM2: out = Ob @ woutT^T + bias -> fp32 ----------------
// BM=32, BN=64, BK=32; grid 8x64 = 512 blocks (2/CU).
__global__ __launch_bounds__(256, 4) void gemm_out(const unsigned short* __restrict__ A,
                                                   const unsigned short* __restrict__ Bt,
                                                   const float* __restrict__ bias,
                                                   float* __restrict__ C) {
  constexpr int BK = 32, N = 512, K = 512;
  __shared__ __align__(16) unsigned short As[32 * BK];
  __shared__ __align__(16) unsigned short Bs[64 * BK];
  const int tid = threadIdx.x, lane = tid & 63, wave = tid >> 6;
  const int m0 = blockIdx.y * 32, n0 = blockIdx.x * 64;
  const int wm = (wave >> 1) * 16, wn = (wave & 1) * 32;
  const int li = tid * 8, r = li >> 5, c = li & 31;
  const int fr = lane & 15, fk = (lane >> 4) * 8;

  f32x4 acc[2] = {};

  for (int k0 = 0; k0 < K; k0 += BK) {
    if (tid < 128) async_copy16(A + (size_t)(m0 + r) * K + k0 + c, &As[li]);  // waves 0,1
    async_copy16(Bt + (size_t)(n0 + r) * K + k0 + c, &Bs[li]);
    __syncthreads();
    bf16x8 af, bfr[2];
    af = *(const bf16x8*)&As[(wm + fr) * BK + fk];
#pragma unroll
    for (int j = 0; j < 2; ++j) bfr[j] = *(const bf16x8*)&Bs[(wn + j * 16 + fr) * BK + fk];
#pragma unroll
    for (int j = 0; j < 2; ++j)
      acc[j] = __builtin_amdgcn_mfma_f32_16x16x32_bf16(af, bfr[j], acc[j], 0, 0, 0);
    __syncthreads();
  }

  const int er = (lane >> 4) * 4, ec = lane & 15;
#pragma unroll
  for (int j = 0; j < 2; ++j) {
    const int col = n0 + wn + j * 16 + ec;
    const float b = bias[col];
#pragma unroll
    for (int rr = 0; rr < 4; ++rr) {
      const int row = m0 + wm + er + rr;
      C[(size_t)row * N + col] = acc[j][rr] + b;
    }
  }
}

// ---------------- MFMA flash attention, key-split, precomputed lists ----------------
// Block = (16-pos tile, head-pair). 256 threads = 4 waves = 2 heads x 2 key-halves.
__global__ __launch_bounds__(256) void attn_mfma(const unsigned short* __restrict__ qkv,
                                                 const int* __restrict__ glist,
                                                 const int* __restrict__ gcnt,
                                                 unsigned short* __restrict__ O) {
  __shared__ __align__(16) int list[192];
  __shared__ __align__(16) float mOd[2][16][72];
  __shared__ float mM[2][16], mL[2][16];
  __shared__ int cntS;

  const int tid = threadIdx.x;
  const int hp = blockIdx.y;   // head pair 0..3

  if (blockIdx.x == 128) {  // output row 0 = V(token 0)
    if (tid < 128) O[hp * 128 + tid] = qkv[1024 + hp * 128 + tid];
    return;
  }
  const int pt = blockIdx.x;
  const int f  = pt >> 6;
  const int hh = (pt >> 1) & 31;
  const int w0 = (pt & 1) << 4;
  const int base_i = (f << 10) | (hh << 5) | w0;

  if (tid < 192) list[tid] = glist[pt * 192 + tid];
  if (tid == 0) cntS = gcnt[pt];
  __syncthreads();
  const int nsub = (cntS + 15) >> 4;

  const int lane = tid & 63;
  const int wave = tid >> 6;      // 0..3
  const int hw   = wave >> 1;     // head within pair
  const int half = wave & 1;
  const int head = hp * 2 + hw;
  const int quad = lane >> 4;
  const int ec   = lane & 15;

  const int i_q = base_i + ec;
  const int tq  = min(i_q + 1, 2047);
  const unsigned short* qrow = qkv + (size_t)tq * QKVP + head * 64 + quad * 8;
  const bf16x8 qb0 = *(const bf16x8*)(qrow);
  const bf16x8 qb1 = *(const bf16x8*)(qrow + 32);

  f32x4 Od[4] = {{0,0,0,0},{0,0,0,0},{0,0,0,0},{0,0,0,0}};
  float m = -1e30f, l = 0.0f;

  for (int sub = half; sub < nsub; sub += 2) {
    const int base = sub * 16;
    const int tok_e = list[base + ec];
    const int4 tokv = *(const int4*)&list[base + quad * 4];
    const int tk[4] = {tokv.x, tokv.y, tokv.z, tokv.w};

    f32x4 S = {0, 0, 0, 0};
    {
      const int t0 = (tok_e > 2047) ? 0 : tok_e;
      const unsigned short* kr = qkv + (size_t)t0 * QKVP + 512 + head * 64 + quad * 8;
      const bf16x8 kf0 = *(const bf16x8*)(kr);
      const bf16x8 kf1 = *(const bf16x8*)(kr + 32);
      S = __builtin_amdgcn_mfma_f32_16x16x32_bf16(kf0, qb0, S, 0, 0, 0);
      S = __builtin_amdgcn_mfma_f32_16x16x32_bf16(kf1, qb1, S, 0, 0, 0);
    }

    float Sm[4];
#pragma unroll
    for (int r = 0; r < 4; ++r) {
      const int tok = tk[r];
      const int idx = tok - 1;
      const bool v = (tok == 0) ||
                     ((idx <= i_q) && ((unsigned)((idx & 31) - (w0 + ec) + 2) <= 4u));
      Sm[r] = v ? S[r] * 0.125f : -1e30f;
    }
    float mx = fmaxf(fmaxf(Sm[0], Sm[1]), fmaxf(Sm[2], Sm[3]));
    mx = fmaxf(mx, __shfl_xor(mx, 16, 64));
    mx = fmaxf(mx, __shfl_xor(mx, 32, 64));
    const float mn = fmaxf(m, mx);
    const float corr = __expf(m - mn);
    m = mn;
    const float p0 = __expf(Sm[0] - mn);
    const float p1 = __expf(Sm[1] - mn);
    const float p2 = __expf(Sm[2] - mn);
    const float p3 = __expf(Sm[3] - mn);
    float rs = (p0 + p1) + (p2 + p3);
    rs += __shfl_xor(rs, 16, 64);
    rs += __shfl_xor(rs, 32, 64);
    l = l * corr + rs;

    bf16x8 pf;
    pf[0] = (short)f2b(p0); pf[1] = (short)f2b(p1);
    pf[2] = (short)f2b(p2); pf[3] = (short)f2b(p3);
    pf[4] = 0; pf[5] = 0; pf[6] = 0; pf[7] = 0;

    const unsigned short* vp[4];
#pragma unroll
    for (int j = 0; j < 4; ++j) {
      const int tv = (tk[j] > 2047) ? 0 : tk[j];
      vp[j] = qkv + (size_t)tv * QKVP + 1024 + head * 64 + ec;
    }
#pragma unroll
    for (int dt = 0; dt < 4; ++dt) {
      bf16x8 vf;
#pragma unroll
      for (int j = 0; j < 4; ++j) vf[j] = (short)vp[j][dt * 16];
      vf[4] = 0; vf[5] = 0; vf[6] = 0; vf[7] = 0;
#pragma unroll
      for (int r = 0; r < 4; ++r) Od[dt][r] *= corr;
      Od[dt] = __builtin_amdgcn_mfma_f32_16x16x32_bf16(vf, pf, Od[dt], 0, 0, 0);
    }
  }

  // merge the two key-halves of this head
  if (half == 1) {
#pragma unroll
    for (int dt = 0; dt < 4; ++dt)
      *(f32x4*)&mOd[hw][ec][dt * 16 + quad * 4] = Od[dt];
    if (quad == 0) { mM[hw][ec] = m; mL[hw][ec] = l; }
  }
  __syncthreads();
  if (half == 0 && i_q <= 2046) {
    const float m1 = mM[hw][ec], l1 = mL[hw][ec];
    const float mm = fmaxf(m, m1);
    const float c0 = __expf(m - mm), c1 = __expf(m1 - mm);
    const float rl = 1.0f / (l * c0 + l1 * c1);
    unsigned short* ob = O + (size_t)(i_q + 1) * 512 + head * 64 + quad * 4;
#pragma unroll
    for (int dt = 0; dt < 4; ++dt) {
      const f32x4 o1 = *(const f32x4*)&mOd[hw][ec][dt * 16 + quad * 4];
      ushort4 u;
      u.x = f2b((Od[dt][0] * c0 + o1[0] * c1) * rl);
      u.y = f2b((Od[dt][1] * c0 + o1[1] * c1) * rl);
      u.z = f2b((Od[dt][2] * c0 + o1[2] * c1) * rl);
      u.w = f2b((Od[dt][3] * c0 + o1[3] * c1) * rl);
      *(ushort4*)(ob + dt * 16) = u;
    }
  }
}

// ---------------- launch ----------------

extern "C" void kernel_launch(void* const* d_in, const int* in_sizes, int n_in,
                              void* d_out, int out_size, void* d_ws, size_t ws_size,
                              hipStream_t stream) {
  const float* x     = (const float*)d_in[0];
  const float* w_qkv = (const float*)d_in[1];
  const float* w_out = (const float*)d_in[2];
  const float* b_out = (const float*)d_in[3];
  float* out = (float*)d_out;

  char* ws = (char*)d_ws;
  unsigned short* qkvb  = (unsigned short*)(ws);              // 2048x1536 bf16
  unsigned short* wqkvT = (unsigned short*)(ws + 6291456);    // 1536x512
  unsigned short* woutT = (unsigned short*)(ws + 7864320);    // 512x512
  unsigned short* Ob    = (unsigned short*)(ws + 8388608);    // 2048x512
  unsigned short* xb    = (unsigned short*)(ws + 10485760);   // 2048x512
  int*            glist = (int*)(ws + 12582912);              // 128x192 int
  int*            gcnt  = (int*)(ws + 12681216);              // 128 int

  hipLaunchKernelGGL(prep, dim3(2176), dim3(256), 0, stream,
                     w_qkv, w_out, x, wqkvT, woutT, xb, glist, gcnt);

  hipLaunchKernelGGL(gemm_qkv, dim3(24, 32), dim3(256), 0, stream, xb, wqkvT, qkvb);

  hipLaunchKernelGGL(attn_mfma, dim3(129, 4), dim3(256), 0, stream, qkvb, glist, gcnt, Ob);

  hipLaunchKernelGGL(gemm_out, dim3(8, 64), dim3(256), 0, stream, Ob, woutT, b_out, out);
}